// Round 1
// baseline (143.103 us; speedup 1.0000x reference)
//
#include <hip/hip_runtime.h>

// Multi-scale parabolic morphological closing, 2-dispatch fused pipeline.
// Algebra: dilations along different axes commute (max-plus), as do erosions
// (min-plus):  closing = ev.eh.dv.dh = (eh.ev).(dh.dv).
// Both groups are "vertical pass then horizontal pass", so each is one fused
// kernel of the proven k2 structure: per-column v-pass from global (clamped
// branchless loads), then row-local h-pass through an LDS tile.
//   K_dil: ws  = dh(dv(x))      (both max)
//   K_ero: out = eh(ev(ws))     (both min)
// weight(d) = c * (4/W^2) * d^2 — product is exact (pow2 * small int), so the
// only deviation vs ref is ~1-ulp fmaf association order from the commutation.
//
// R5 changes vs R4 (123.7us, 3 dispatches):
//  (a) 3 -> 2 dispatches via the commutation above: removes one dispatch ramp
//      and 67 MB of intermediate HBM/L3 round-trip (k1's write + k2's read).
//  (b) 1-D grid, scale k = bid & 3 (fastest-varying): every CU's resident set
//      mixes W={4,8,16,32}; kills the all-W=32 tail that z-major scheduling
//      produced (W=32 blocks do ~7x the taps of W=4).
// R4 counters: k2 VALUBusy 44%, occupancy 62%, HBM 12% of peak, LDS conflicts
// 0.002% of cycles -> latency/ramp/imbalance bound, not any throughput limit.

#define HH 256
#define WW 256
#define BC 32
#define NS 4
#define HW (HH * WW)
#define SLICE ((long)BC * HW)
#define LSTR 324   // LDS row stride: 2*32+256+4

// ---- core: horizontal pass over one padded LDS row; thread computes 8 outputs ----
// lw = row base + 8*t ; offset o in [0, 2W+8) maps to d = o - W - pp
template <int W, bool IS_MAX>
__device__ __forceinline__ void hpass_lds(const float* __restrict__ lw, float cw,
                                          float acc[8])
{
    const float PAD = IS_MAX ? -1e30f : 1e30f;
#pragma unroll
    for (int pp = 0; pp < 8; ++pp) acc[pp] = PAD;
#pragma unroll
    for (int u = 0; u < (8 + 2 * W) / 2; ++u) {
        const float2 v = *(const float2*)(lw + 2 * u);
#pragma unroll
        for (int pp = 0; pp < 8; ++pp) {
            const int d1 = 2 * u - W - pp;
            const int d2 = d1 + 1;
            const bool ok1 = (d1 >= -W) && (d1 <= W);
            const bool ok2 = (d2 >= -W) && (d2 <= W);
            const float K1 = (float)(d1 * d1);
            const float K2 = (float)(d2 * d2);
            if (ok1 && ok2) {
                const float c1 = IS_MAX ? fmaf(cw, -K1, v.x) : fmaf(cw, K1, v.x);
                const float c2 = IS_MAX ? fmaf(cw, -K2, v.y) : fmaf(cw, K2, v.y);
                acc[pp] = IS_MAX ? fmaxf(fmaxf(acc[pp], c1), c2)
                                 : fminf(fminf(acc[pp], c1), c2);
            } else if (ok1) {
                const float c1 = IS_MAX ? fmaf(cw, -K1, v.x) : fmaf(cw, K1, v.x);
                acc[pp] = IS_MAX ? fmaxf(acc[pp], c1) : fminf(acc[pp], c1);
            } else if (ok2) {
                const float c2 = IS_MAX ? fmaf(cw, -K2, v.y) : fmaf(cw, K2, v.y);
                acc[pp] = IS_MAX ? fmaxf(acc[pp], c2) : fminf(acc[pp], c2);
            }
        }
    }
}

// ---- core: vertical pass; thread = one column, 8 consecutive output rows ----
template <int W, bool IS_MAX>
__device__ __forceinline__ void vpass_core(const float* __restrict__ img, int x,
                                           int h0, float cw, float acc[8])
{
    const float PAD = IS_MAX ? -1e30f : 1e30f;
#pragma unroll
    for (int pp = 0; pp < 8; ++pp) acc[pp] = PAD;
#pragma unroll
    for (int ch = 0; ch < (8 + 2 * W) / 8; ++ch) {
        float v[8];
#pragma unroll
        for (int q = 0; q < 8; ++q) {        // batched branchless clamped loads
            const int h = h0 + ch * 8 + q - W;
            const int hc = min(max(h, 0), HH - 1);
            const float tv = img[(long)hc * WW + x];
            v[q] = (h == hc) ? tv : PAD;
        }
#pragma unroll
        for (int pp = 0; pp < 8; ++pp) {
#pragma unroll
            for (int q = 0; q < 8; q += 2) {
                const int d1 = ch * 8 + q - W - pp;
                const int d2 = d1 + 1;
                const bool ok1 = (d1 >= -W) && (d1 <= W);
                const bool ok2 = (d2 >= -W) && (d2 <= W);
                const float K1 = (float)(d1 * d1);
                const float K2 = (float)(d2 * d2);
                if (ok1 && ok2) {
                    const float c1 = IS_MAX ? fmaf(cw, -K1, v[q])     : fmaf(cw, K1, v[q]);
                    const float c2 = IS_MAX ? fmaf(cw, -K2, v[q + 1]) : fmaf(cw, K2, v[q + 1]);
                    acc[pp] = IS_MAX ? fmaxf(fmaxf(acc[pp], c1), c2)
                                     : fminf(fminf(acc[pp], c1), c2);
                } else if (ok1) {
                    const float c1 = IS_MAX ? fmaf(cw, -K1, v[q]) : fmaf(cw, K1, v[q]);
                    acc[pp] = IS_MAX ? fmaxf(acc[pp], c1) : fminf(acc[pp], c1);
                } else if (ok2) {
                    const float c2 = IS_MAX ? fmaf(cw, -K2, v[q + 1]) : fmaf(cw, K2, v[q + 1]);
                    acc[pp] = IS_MAX ? fmaxf(acc[pp], c2) : fminf(acc[pp], c2);
                }
            }
        }
    }
}

// ---- fused vertical-then-horizontal pass (both max, or both min) ----
template <int W, bool IS_MAX>
__device__ __forceinline__ void vh_impl(const float* __restrict__ img,
                                        float* __restrict__ op_base,
                                        int h0, float c, float* lbuf)
{
    const int x = threadIdx.x;
    const float cw = c * (4.0f / (float)(W * W));
    const float PAD = IS_MAX ? -1e30f : 1e30f;

    // phase 1: vertical pass for 8 rows (thread-per-column)
    float vacc[8];
    vpass_core<W, IS_MAX>(img, x, h0, cw, vacc);

    // stash as padded LDS rows for the horizontal pass
#pragma unroll
    for (int q = 0; q < 8; ++q) lbuf[q * LSTR + W + x] = vacc[q];
    if (x < W) {
#pragma unroll
        for (int q = 0; q < 8; ++q) {
            lbuf[q * LSTR + x] = PAD;
            lbuf[q * LSTR + W + 256 + x] = PAD;
        }
    }
    __syncthreads();

    // phase 2: horizontal pass on the 8-row tile
    const int r = threadIdx.x >> 5, t = threadIdx.x & 31;
    float acc[8];
    hpass_lds<W, IS_MAX>(lbuf + r * LSTR + 8 * t, cw, acc);
    float* op = op_base + (long)(h0 + r) * WW + 8 * t;
    *(float4*)(op)     = make_float4(acc[0], acc[1], acc[2], acc[3]);
    *(float4*)(op + 4) = make_float4(acc[4], acc[5], acc[6], acc[7]);
}

// ---- kernel: 1-D grid, scale varies fastest for per-CU load balance ----
// bid -> k = kbase + (bid & (2^kbits-1)); z = zbase + (...); y = remainder.
template <bool IS_MAX>
__global__ __launch_bounds__(256, 4) void k_vh(const float* __restrict__ in,
                                               float* __restrict__ out,
                                               const float* __restrict__ cptr,
                                               long in_ks, long in_zs,
                                               long out_ks, long out_zs,
                                               int kbase, int kbits,
                                               int zbase, int zbits)
{
    __shared__ float lbuf[8 * LSTR];
    const int bid = blockIdx.x;
    const int k = kbase + (bid & ((1 << kbits) - 1));
    const int rest = bid >> kbits;
    const int z = zbase + (rest & ((1 << zbits) - 1));
    const int y = rest >> zbits;
    const int h0 = y * 8;
    const float c = cptr[0];
    const float* ip = in + (long)k * in_ks + (long)z * in_zs;
    float* op = out + (long)k * out_ks + (long)z * out_zs;
    switch (k) {
        case 0: vh_impl<4,  IS_MAX>(ip, op, h0, c, lbuf); break;
        case 1: vh_impl<8,  IS_MAX>(ip, op, h0, c, lbuf); break;
        case 2: vh_impl<16, IS_MAX>(ip, op, h0, c, lbuf); break;
        case 3: vh_impl<32, IS_MAX>(ip, op, h0, c, lbuf); break;
    }
}

extern "C" void kernel_launch(void* const* d_in, const int* in_sizes, int n_in,
                              void* d_out, int out_size, void* d_ws, size_t ws_size,
                              hipStream_t stream)
{
    const float* x = (const float*)d_in[0];   // [4,8,256,256] fp32
    const float* c = (const float*)d_in[1];   // scalar se_coef
    float* out = (float*)d_out;               // [4,8,4,256,256] fp32
    float* ws  = (float*)d_ws;

    dim3 b(256);
    const size_t slice_b = (size_t)SLICE * sizeof(float);        // 8.4 MB
    if (ws_size >= (size_t)NS * slice_b) {
        // main path: 2 dispatches over all 4 scales, scale-interleaved 1-D grid
        dim3 g(NS * BC * (HH / 8));                              // 4096 blocks
        // K_dil: ws[k,z] = dh(dv(x[z]))   (x shared across scales: in_ks = 0)
        k_vh<true ><<<g, b, 0, stream>>>(x,  ws,  c, 0,     HW, SLICE, HW,
                                         0, 2, 0, 5);
        // K_ero: out[z,k] = eh(ev(ws[k,z]))
        k_vh<false><<<g, b, 0, stream>>>(ws, out, c, SLICE, HW, HW, (long)NS * HW,
                                         0, 2, 0, 5);
    } else if (ws_size >= slice_b) {
        // per-scale fallback: one 8.4 MB ws slice reused across scales
        dim3 g(BC * (HH / 8));
        for (int k = 0; k < NS; ++k) {
            k_vh<true ><<<g, b, 0, stream>>>(x,  ws,  c, 0, HW, 0, HW,
                                             k, 0, 0, 5);
            k_vh<false><<<g, b, 0, stream>>>(ws, out, c, 0, HW, HW, (long)NS * HW,
                                             k, 0, 0, 5);
        }
    } else {
        // emergency fallback: one 256 KB slice per (scale, z) pair
        dim3 g(HH / 8);
        for (int k = 0; k < NS; ++k)
            for (int z = 0; z < BC; ++z) {
                k_vh<true ><<<g, b, 0, stream>>>(x,  ws,  c, 0, HW, 0, 0,
                                                 k, 0, z, 0);
                k_vh<false><<<g, b, 0, stream>>>(ws, out, c, 0, 0, HW, (long)NS * HW,
                                                 k, 0, z, 0);
            }
    }
}

// Round 2
// 133.045 us; speedup vs baseline: 1.0756x; 1.0756x over previous
//
#include <hip/hip_runtime.h>

// Multi-scale parabolic morphological closing, 2-dispatch fused pipeline.
// Algebra: dilations along different axes commute (max-plus), as do erosions:
//   closing = ev.eh.dv.dh = (eh.ev).(dh.dv)
// Each group is one fused kernel: per-column v-pass from global (coalesced
// across lanes), then row-local h-pass through an LDS tile.
//   K_dil: ws  = dh(dv(x))      (both max)
//   K_ero: out = eh(ev(ws))     (both min)
// weight(d) = c * (4/W^2) * d^2 — pow2 * small-int products are exact.
//
// R6 (from R5 post-mortem): dur 143.1 = poison-fill(48, harness, fixed tax)
// + 2 x v+h kernel(~47 each). v+h kernels are STALL-bound: VALUBusy 44%,
// occupancy 62%, HBM 12%, LDS conflicts ~0. Fixes, all bit-exact (candidate
// order unchanged):
//  (a) __launch_bounds__(256,8): 16->32 waves/CU (VGPR was 32 <= 64 cap,
//      LDS 10.75KB*8 = 86KB < 160KB) — latency hiding for v-pass loads+sync.
//  (b) interior-block fast path: blocks whose +-W row range is fully
//      in-bounds (75-94% of blocks) skip the clamp/select VALU per load.
//  (c) h-pass reads LDS as float4 (b128) instead of float2 — half the LDS
//      instructions; LSTR=324 and 8*t keep 16B alignment.

#define HH 256
#define WW 256
#define BC 32
#define NS 4
#define HW (HH * WW)
#define SLICE ((long)BC * HW)
#define LSTR 324   // LDS row stride in floats: 2*32+256+4 (multiple of 4 -> 16B rows)

// ---- horizontal pass over one padded LDS row; thread computes 8 outputs ----
// lw = row base + 8*t (16B-aligned); element o in [0, 2W+8) maps to d = o - W - pp
template <int W, bool IS_MAX>
__device__ __forceinline__ void hpass_lds(const float* __restrict__ lw, float cw,
                                          float acc[8])
{
    const float PAD = IS_MAX ? -1e30f : 1e30f;
#pragma unroll
    for (int pp = 0; pp < 8; ++pp) acc[pp] = PAD;
#pragma unroll
    for (int u = 0; u < (8 + 2 * W) / 4; ++u) {
        const float4 vv = *(const float4*)(lw + 4 * u);
        const float vs[4] = {vv.x, vv.y, vv.z, vv.w};
#pragma unroll
        for (int pp = 0; pp < 8; ++pp) {
#pragma unroll
            for (int e = 0; e < 4; ++e) {
                const int d = 4 * u + e - W - pp;          // compile-time
                if (d >= -W && d <= W) {
                    const float K = (float)(d * d);
                    const float cand = IS_MAX ? fmaf(cw, -K, vs[e])
                                              : fmaf(cw,  K, vs[e]);
                    acc[pp] = IS_MAX ? fmaxf(acc[pp], cand) : fminf(acc[pp], cand);
                }
            }
        }
    }
}

// ---- vertical pass; thread = one column, 8 consecutive output rows ----
// CLAMP=false: caller guarantees rows [h0-W, h0+7+W] are all in-bounds.
template <int W, bool IS_MAX, bool CLAMP>
__device__ __forceinline__ void vpass_core(const float* __restrict__ img, int x,
                                           int h0, float cw, float acc[8])
{
    const float PAD = IS_MAX ? -1e30f : 1e30f;
#pragma unroll
    for (int pp = 0; pp < 8; ++pp) acc[pp] = PAD;
#pragma unroll
    for (int ch = 0; ch < (8 + 2 * W) / 8; ++ch) {
        float v[8];
#pragma unroll
        for (int q = 0; q < 8; ++q) {
            const int h = h0 + ch * 8 + q - W;
            if (CLAMP) {                    // branchless clamped load
                const int hc = min(max(h, 0), HH - 1);
                const float tv = img[(long)hc * WW + x];
                v[q] = (h == hc) ? tv : PAD;
            } else {                        // interior: plain load
                v[q] = img[(long)h * WW + x];
            }
        }
#pragma unroll
        for (int pp = 0; pp < 8; ++pp) {
#pragma unroll
            for (int q = 0; q < 8; ++q) {
                const int d = ch * 8 + q - W - pp;          // compile-time
                if (d >= -W && d <= W) {
                    const float K = (float)(d * d);
                    const float cand = IS_MAX ? fmaf(cw, -K, v[q])
                                              : fmaf(cw,  K, v[q]);
                    acc[pp] = IS_MAX ? fmaxf(acc[pp], cand) : fminf(acc[pp], cand);
                }
            }
        }
    }
}

// ---- fused vertical-then-horizontal pass (both max, or both min) ----
template <int W, bool IS_MAX>
__device__ __forceinline__ void vh_impl(const float* __restrict__ img,
                                        float* __restrict__ op_base,
                                        int h0, float c, float* lbuf)
{
    const int x = threadIdx.x;
    const float cw = c * (4.0f / (float)(W * W));
    const float PAD = IS_MAX ? -1e30f : 1e30f;

    // phase 1: vertical pass for 8 rows (thread-per-column)
    float vacc[8];
    if (h0 >= W && h0 + 8 + W <= HH)        // block-uniform branch
        vpass_core<W, IS_MAX, false>(img, x, h0, cw, vacc);
    else
        vpass_core<W, IS_MAX, true >(img, x, h0, cw, vacc);

    // stash as padded LDS rows for the horizontal pass
#pragma unroll
    for (int q = 0; q < 8; ++q) lbuf[q * LSTR + W + x] = vacc[q];
    if (x < W) {
#pragma unroll
        for (int q = 0; q < 8; ++q) {
            lbuf[q * LSTR + x] = PAD;
            lbuf[q * LSTR + W + 256 + x] = PAD;
        }
    }
    __syncthreads();

    // phase 2: horizontal pass on the 8-row tile
    const int r = threadIdx.x >> 5, t = threadIdx.x & 31;
    float acc[8];
    hpass_lds<W, IS_MAX>(lbuf + r * LSTR + 8 * t, cw, acc);
    float* op = op_base + (long)(h0 + r) * WW + 8 * t;
    *(float4*)(op)     = make_float4(acc[0], acc[1], acc[2], acc[3]);
    *(float4*)(op + 4) = make_float4(acc[4], acc[5], acc[6], acc[7]);
}

// ---- kernel: 1-D grid, scale varies fastest for per-CU load balance ----
// bid -> k = kbase + (bid & (2^kbits-1)); z = zbase + (...); y = remainder.
template <bool IS_MAX>
__global__ __launch_bounds__(256, 8) void k_vh(const float* __restrict__ in,
                                               float* __restrict__ out,
                                               const float* __restrict__ cptr,
                                               long in_ks, long in_zs,
                                               long out_ks, long out_zs,
                                               int kbase, int kbits,
                                               int zbase, int zbits)
{
    __shared__ float lbuf[8 * LSTR];
    const int bid = blockIdx.x;
    const int k = kbase + (bid & ((1 << kbits) - 1));
    const int rest = bid >> kbits;
    const int z = zbase + (rest & ((1 << zbits) - 1));
    const int y = rest >> zbits;
    const int h0 = y * 8;
    const float c = cptr[0];
    const float* ip = in + (long)k * in_ks + (long)z * in_zs;
    float* op = out + (long)k * out_ks + (long)z * out_zs;
    switch (k) {
        case 0: vh_impl<4,  IS_MAX>(ip, op, h0, c, lbuf); break;
        case 1: vh_impl<8,  IS_MAX>(ip, op, h0, c, lbuf); break;
        case 2: vh_impl<16, IS_MAX>(ip, op, h0, c, lbuf); break;
        case 3: vh_impl<32, IS_MAX>(ip, op, h0, c, lbuf); break;
    }
}

extern "C" void kernel_launch(void* const* d_in, const int* in_sizes, int n_in,
                              void* d_out, int out_size, void* d_ws, size_t ws_size,
                              hipStream_t stream)
{
    const float* x = (const float*)d_in[0];   // [4,8,256,256] fp32
    const float* c = (const float*)d_in[1];   // scalar se_coef
    float* out = (float*)d_out;               // [4,8,4,256,256] fp32
    float* ws  = (float*)d_ws;

    dim3 b(256);
    const size_t slice_b = (size_t)SLICE * sizeof(float);        // 8.4 MB
    if (ws_size >= (size_t)NS * slice_b) {
        // main path: 2 dispatches over all 4 scales, scale-interleaved 1-D grid
        dim3 g(NS * BC * (HH / 8));                              // 4096 blocks
        // K_dil: ws[k,z] = dh(dv(x[z]))   (x shared across scales: in_ks = 0)
        k_vh<true ><<<g, b, 0, stream>>>(x,  ws,  c, 0,     HW, SLICE, HW,
                                         0, 2, 0, 5);
        // K_ero: out[z,k] = eh(ev(ws[k,z]))
        k_vh<false><<<g, b, 0, stream>>>(ws, out, c, SLICE, HW, HW, (long)NS * HW,
                                         0, 2, 0, 5);
    } else if (ws_size >= slice_b) {
        // per-scale fallback: one 8.4 MB ws slice reused across scales
        dim3 g(BC * (HH / 8));
        for (int k = 0; k < NS; ++k) {
            k_vh<true ><<<g, b, 0, stream>>>(x,  ws,  c, 0, HW, 0, HW,
                                             k, 0, 0, 5);
            k_vh<false><<<g, b, 0, stream>>>(ws, out, c, 0, HW, HW, (long)NS * HW,
                                             k, 0, 0, 5);
        }
    } else {
        // emergency fallback: one 256 KB slice per (scale, z) pair
        dim3 g(HH / 8);
        for (int k = 0; k < NS; ++k)
            for (int z = 0; z < BC; ++z) {
                k_vh<true ><<<g, b, 0, stream>>>(x,  ws,  c, 0, HW, 0, 0,
                                                 k, 0, z, 0);
                k_vh<false><<<g, b, 0, stream>>>(ws, out, c, 0, 0, HW, (long)NS * HW,
                                                 k, 0, z, 0);
            }
    }
}

// Round 3
// 119.808 us; speedup vs baseline: 1.1944x; 1.1105x over previous
//
#include <hip/hip_runtime.h>

// Multi-scale parabolic morphological closing, 2-dispatch fused pipeline.
// Algebra: dilations along different axes commute (max-plus), as do erosions:
//   closing = ev.eh.dv.dh = (eh.ev).(dh.dv)
//   K_dil: ws  = dh(dv(x))      (both max)
//   K_ero: out = eh(ev(ws))     (both min)
// weight(d) = c * (4/W^2) * d^2 — pow2 * small-int products are exact.
//
// R7 (from R6 post-mortem): dur 133 = fill(49, harness tax) + 2 x k_vh(~42).
// k_vh busy-time is already near the ~20us VALU-issue floor (3 VALU/tap);
// the 2x wall-clock gap is structural bubbles: per-block cost ratio 7.2:1
// across scales (W=32 vs W=4), 4096 blocks = 2 uneven residency rounds,
// heavy tail. Fix: EQUAL-WORK BLOCKS — each block runs NT={8,4,2,1}
// consecutive tiles for W={4,8,16,32} (work 72/68/66/65 tap-units, uniform
// within 10%), grid = 60 blocks/z * 32 z = 1920 <= 2048 resident capacity:
// single residency round, no tail, ramp amortized. Consecutive tiles share
// +-W halo rows (cache hits). Math untouched -> bit-exact (absmax 0.0).

#define HH 256
#define WW 256
#define BC 32
#define NS 4
#define HW (HH * WW)
#define SLICE ((long)BC * HW)
#define LSTR 324   // LDS row stride in floats: 2*32+256+4 (16B-aligned rows)

// ---- horizontal pass over one padded LDS row; thread computes 8 outputs ----
// lw = row base + 8*t (16B-aligned); element o in [0, 2W+8) maps to d = o - W - pp
template <int W, bool IS_MAX>
__device__ __forceinline__ void hpass_lds(const float* __restrict__ lw, float cw,
                                          float acc[8])
{
    const float PAD = IS_MAX ? -1e30f : 1e30f;
#pragma unroll
    for (int pp = 0; pp < 8; ++pp) acc[pp] = PAD;
#pragma unroll
    for (int u = 0; u < (8 + 2 * W) / 4; ++u) {
        const float4 vv = *(const float4*)(lw + 4 * u);
        const float vs[4] = {vv.x, vv.y, vv.z, vv.w};
#pragma unroll
        for (int pp = 0; pp < 8; ++pp) {
#pragma unroll
            for (int e = 0; e < 4; ++e) {
                const int d = 4 * u + e - W - pp;          // compile-time
                if (d >= -W && d <= W) {
                    const float K = (float)(d * d);
                    const float cand = IS_MAX ? fmaf(cw, -K, vs[e])
                                              : fmaf(cw,  K, vs[e]);
                    acc[pp] = IS_MAX ? fmaxf(acc[pp], cand) : fminf(acc[pp], cand);
                }
            }
        }
    }
}

// ---- vertical pass; thread = one column, 8 consecutive output rows ----
// CLAMP=false: caller guarantees rows [h0-W, h0+7+W] are all in-bounds.
template <int W, bool IS_MAX, bool CLAMP>
__device__ __forceinline__ void vpass_core(const float* __restrict__ img, int x,
                                           int h0, float cw, float acc[8])
{
    const float PAD = IS_MAX ? -1e30f : 1e30f;
#pragma unroll
    for (int pp = 0; pp < 8; ++pp) acc[pp] = PAD;
#pragma unroll
    for (int ch = 0; ch < (8 + 2 * W) / 8; ++ch) {
        float v[8];
#pragma unroll
        for (int q = 0; q < 8; ++q) {
            const int h = h0 + ch * 8 + q - W;
            if (CLAMP) {                    // branchless clamped load
                const int hc = min(max(h, 0), HH - 1);
                const float tv = img[(long)hc * WW + x];
                v[q] = (h == hc) ? tv : PAD;
            } else {                        // interior: plain load
                v[q] = img[(long)h * WW + x];
            }
        }
#pragma unroll
        for (int pp = 0; pp < 8; ++pp) {
#pragma unroll
            for (int q = 0; q < 8; ++q) {
                const int d = ch * 8 + q - W - pp;          // compile-time
                if (d >= -W && d <= W) {
                    const float K = (float)(d * d);
                    const float cand = IS_MAX ? fmaf(cw, -K, v[q])
                                              : fmaf(cw,  K, v[q]);
                    acc[pp] = IS_MAX ? fmaxf(acc[pp], cand) : fminf(acc[pp], cand);
                }
            }
        }
    }
}

// ---- one fused v-then-h tile: 8 rows x 256 cols ----
template <int W, bool IS_MAX>
__device__ __forceinline__ void vh_tile(const float* __restrict__ img,
                                        float* __restrict__ op_base,
                                        int h0, float cw, float* lbuf)
{
    const int x = threadIdx.x;
    const float PAD = IS_MAX ? -1e30f : 1e30f;

    // phase 1: vertical pass for 8 rows (thread-per-column)
    float vacc[8];
    if (h0 >= W && h0 + 8 + W <= HH)        // block-uniform branch
        vpass_core<W, IS_MAX, false>(img, x, h0, cw, vacc);
    else
        vpass_core<W, IS_MAX, true >(img, x, h0, cw, vacc);

    // stash as padded LDS rows for the horizontal pass
#pragma unroll
    for (int q = 0; q < 8; ++q) lbuf[q * LSTR + W + x] = vacc[q];
    if (x < W) {
#pragma unroll
        for (int q = 0; q < 8; ++q) {
            lbuf[q * LSTR + x] = PAD;
            lbuf[q * LSTR + W + 256 + x] = PAD;
        }
    }
    __syncthreads();

    // phase 2: horizontal pass on the 8-row tile
    const int r = threadIdx.x >> 5, t = threadIdx.x & 31;
    float acc[8];
    hpass_lds<W, IS_MAX>(lbuf + r * LSTR + 8 * t, cw, acc);
    float* op = op_base + (long)(h0 + r) * WW + 8 * t;
    *(float4*)(op)     = make_float4(acc[0], acc[1], acc[2], acc[3]);
    *(float4*)(op + 4) = make_float4(acc[4], acc[5], acc[6], acc[7]);

    __syncthreads();                        // lbuf reused by next tile
}

// ---- NT consecutive tiles per block (equal-work scheduling) ----
template <int W, bool IS_MAX, int NT>
__device__ __forceinline__ void run_tiles(const float* __restrict__ ip,
                                          float* __restrict__ op,
                                          int y0, float c, float* lbuf)
{
    const float cw = c * (4.0f / (float)(W * W));
#pragma unroll 1
    for (int i = 0; i < NT; ++i)
        vh_tile<W, IS_MAX>(ip, op, (y0 + i) * 8, cw, lbuf);
}

// ---- kernel ----
// kfix < 0 : full decode, 60 equal-work blocks per z-slice:
//   r<32 -> k=3 (1 tile); r<48 -> k=2 (2 tiles); r<56 -> k=1 (4); else k=0 (8)
// kfix >= 0: single-scale mode, bpz blocks per z, z = zbase + bid/bpz.
template <bool IS_MAX>
__global__ __launch_bounds__(256, 8) void k_vh(const float* __restrict__ in,
                                               float* __restrict__ out,
                                               const float* __restrict__ cptr,
                                               long in_ks, long in_zs,
                                               long out_ks, long out_zs,
                                               int kfix, int bpz, int zbase)
{
    __shared__ float lbuf[8 * LSTR];
    const int bid = blockIdx.x;
    int k, y0, z;
    if (kfix < 0) {
        z = bid / 60;
        const int r = bid - z * 60;
        if (r < 32)      { k = 3; y0 = r; }
        else if (r < 48) { k = 2; y0 = (r - 32) * 2; }
        else if (r < 56) { k = 1; y0 = (r - 48) * 4; }
        else             { k = 0; y0 = (r - 56) * 8; }
    } else {
        k = kfix;
        const int zi = bid / bpz;
        const int yi = bid - zi * bpz;
        z = zbase + zi;
        y0 = yi * (32 / bpz);
    }
    const float c = cptr[0];
    const float* ip = in + (long)k * in_ks + (long)z * in_zs;
    float* op = out + (long)k * out_ks + (long)z * out_zs;
    switch (k) {
        case 0: run_tiles<4,  IS_MAX, 8>(ip, op, y0, c, lbuf); break;
        case 1: run_tiles<8,  IS_MAX, 4>(ip, op, y0, c, lbuf); break;
        case 2: run_tiles<16, IS_MAX, 2>(ip, op, y0, c, lbuf); break;
        case 3: run_tiles<32, IS_MAX, 1>(ip, op, y0, c, lbuf); break;
    }
}

extern "C" void kernel_launch(void* const* d_in, const int* in_sizes, int n_in,
                              void* d_out, int out_size, void* d_ws, size_t ws_size,
                              hipStream_t stream)
{
    const float* x = (const float*)d_in[0];   // [4,8,256,256] fp32
    const float* c = (const float*)d_in[1];   // scalar se_coef
    float* out = (float*)d_out;               // [4,8,4,256,256] fp32
    float* ws  = (float*)d_ws;

    dim3 b(256);
    const size_t slice_b = (size_t)SLICE * sizeof(float);        // 8.4 MB
    if (ws_size >= (size_t)NS * slice_b) {
        // main path: 2 dispatches, 60 equal-work blocks per z => 1920 blocks
        dim3 g(60 * BC);
        // K_dil: ws[k,z] = dh(dv(x[z]))   (x shared across scales: in_ks = 0)
        k_vh<true ><<<g, b, 0, stream>>>(x,  ws,  c, 0,     HW, SLICE, HW,
                                         -1, 0, 0);
        // K_ero: out[z,k] = eh(ev(ws[k,z]))
        k_vh<false><<<g, b, 0, stream>>>(ws, out, c, SLICE, HW, HW, (long)NS * HW,
                                         -1, 0, 0);
    } else if (ws_size >= slice_b) {
        // per-scale fallback: one 8.4 MB ws slice reused across scales
        for (int k = 0; k < NS; ++k) {
            const int bpz = 4 << k;                 // blocks per z-slice
            dim3 g(bpz * BC);
            k_vh<true ><<<g, b, 0, stream>>>(x,  ws,  c, 0, HW, 0, HW,
                                             k, bpz, 0);
            k_vh<false><<<g, b, 0, stream>>>(ws, out, c, 0, HW, HW, (long)NS * HW,
                                             k, bpz, 0);
        }
    } else {
        // emergency fallback: one 256 KB ws tile per (scale, z) pair
        for (int k = 0; k < NS; ++k) {
            const int bpz = 4 << k;
            dim3 g(bpz);
            for (int z = 0; z < BC; ++z) {
                k_vh<true ><<<g, b, 0, stream>>>(x,  ws,  c, 0, HW, 0, 0,
                                                 k, bpz, z);
                k_vh<false><<<g, b, 0, stream>>>(ws, out, c, 0, 0, HW, (long)NS * HW,
                                                 k, bpz, z);
            }
        }
    }
}